// Round 1
// baseline (87.774 us; speedup 1.0000x reference)
//
#include <hip/hip_runtime.h>

typedef __attribute__((ext_vector_type(8))) short short8;
typedef __attribute__((ext_vector_type(4))) float f32x4;

// ---------------- ws layout (bytes) ----------------
// rcp  : float [8][512]                      @ 0         (16384)
// wpre : bf16  [c=8][t=9][kb=8][co=512][8]   @ 16384     (4718592)
// xm   : bf16  [b=8][g=64][h=32][col=34][8]  @ 4734976   (8912896)
#define RCP_OFF   0
#define WPRE_OFF  16384
#define XM_OFF    4734976

__device__ __forceinline__ unsigned short f2bf(float f) {
  unsigned int u = __float_as_uint(f);
  u += 0x7FFFu + ((u >> 16) & 1u);       // round-to-nearest-even
  return (unsigned short)(u >> 16);
}

__device__ __forceinline__ void gload_lds16(const void* g, void* l) {
  __builtin_amdgcn_global_load_lds(
      (__attribute__((address_space(1))) void*)g,
      (__attribute__((address_space(3))) void*)l, 16, 0, 0);
}

// ---------------- prep 1: demod rcp[b][o] ----------------
__global__ void xs_kernel(const float* __restrict__ w, const float* __restrict__ ys,
                          float* __restrict__ rcp) {
  int o = blockIdx.x;
  int tid = threadIdx.x;
  __shared__ float w2s[512];
  __shared__ float red[256];
  const float scale2 = 1.0f / 4608.0f;   // (Ci*K*K)^-1
  for (int ci = tid; ci < 512; ci += 256) {
    const float* wp = w + (size_t)(o * 512 + ci) * 9;
    float s = 0.f;
#pragma unroll
    for (int k = 0; k < 9; ++k) s += wp[k] * wp[k];
    w2s[ci] = s * scale2;
  }
  __syncthreads();
  for (int b = 0; b < 8; ++b) {
    float part = 0.f;
    for (int ci = tid; ci < 512; ci += 256) {
      float y = ys[b * 512 + ci];
      part += y * y * w2s[ci];
    }
    red[tid] = part;
    __syncthreads();
    for (int s = 128; s > 0; s >>= 1) {
      if (tid < s) red[tid] += red[tid + s];
      __syncthreads();
    }
    if (tid == 0) rcp[b * 512 + o] = 1.0f / sqrtf(red[0] + 1e-8f);
    __syncthreads();
  }
}

// ---------------- prep 2: modulated x -> bf16, NHWC-grouped, padded cols ----------------
__global__ void xm_kernel(const float* __restrict__ x, const float* __restrict__ ys,
                          unsigned short* __restrict__ xm) {
  int bid = blockIdx.x;            // [b(8)][h(32)][half(2)]
  int half = bid & 1;
  int h = (bid >> 1) & 31;
  int b = bid >> 6;
  int tid = threadIdx.x;
  __shared__ float tile[256][33];
  int ci0 = half * 256;
#pragma unroll
  for (int r = 0; r < 32; ++r) {
    int ci = r * 8 + (tid >> 5);                 // 0..255
    int wcol = tid & 31;
    float v = x[(((size_t)b * 512 + ci0 + ci) * 32 + h) * 32 + wcol];
    tile[ci][wcol] = v * ys[b * 512 + ci0 + ci];
  }
  __syncthreads();
  int g0 = half * 32;
  for (int r = 0; r < 5; ++r) {
    int idx = r * 256 + tid;                     // [gl(32)][col(34)]
    if (idx < 1088) {
      int gl = idx / 34;
      int col = idx - gl * 34;
      short8 v = {0,0,0,0,0,0,0,0};
      if (col != 0 && col != 33) {
        int wcol = col - 1;
#pragma unroll
        for (int j = 0; j < 8; ++j)
          v[j] = (short)f2bf(tile[gl * 8 + j][wcol]);
      }
      size_t off = ((((size_t)b * 64 + g0 + gl) * 32 + h) * 34 + col) * 8;
      *reinterpret_cast<short8*>(xm + off) = v;
    }
  }
}

// ---------------- prep 3: scaled weight -> bf16 fragment layout ----------------
__global__ void wpre_kernel(const float* __restrict__ w, unsigned short* __restrict__ wpre) {
  int bid = blockIdx.x;            // [c(8)][t(9)][kb(8)] = 576
  int kb = bid & 7;
  int t = (bid >> 3) % 9;
  int c = bid / 72;
  int tid = threadIdx.x;
  const float scale = 1.4731391274719738e-02f;   // (512*9)^-0.5
  int ci0 = c * 64 + kb * 8;
#pragma unroll
  for (int r = 0; r < 2; ++r) {
    int co = r * 256 + tid;
    short8 v;
#pragma unroll
    for (int j = 0; j < 8; ++j)
      v[j] = (short)f2bf(scale * w[((size_t)co * 512 + ci0 + j) * 9 + t]);
    size_t off = ((((size_t)c * 9 + t) * 8 + kb) * 512 + co) * 8;
    *reinterpret_cast<short8*>(wpre + off) = v;
  }
}

// ---------------- main: implicit-GEMM direct conv ----------------
// grid 256 = [sp(64)=b*8+hg][cog(4)], block 512 = 8 waves
// block tile: 128 Co x 128 px (4 rows). waves: (wr,wc) 2x2 spatial x kp 2-way K-split.
// xbuf  [kb=8][r=6][col=34][8] bf16 = 26112 B   (r: image rows hg*4-1 .. hg*4+4)
// wbuf2 [2][kb=8][co=128][8] bf16 = 2*16384 B
__global__ __launch_bounds__(512, 2) void conv_main(
    const unsigned short* __restrict__ wpre,
    const unsigned short* __restrict__ xm,
    const float* __restrict__ rcp,
    const float* __restrict__ bias,
    float* __restrict__ out)
{
  __shared__ __align__(16) char smem[58880];
  char* xb = smem;                                   // 26112 B

  int bid = blockIdx.x;
  int cog = bid & 3;
  int sp = bid >> 2;
  int b = sp >> 3;
  int hg = sp & 7;
  int tid = threadIdx.x;
  int lane = tid & 63;
  int wv = tid >> 6;                // 0..7
  int wc = wv & 1;
  int wr = (wv >> 1) & 1;
  int kp = wv >> 2;                 // K-split half
  int l15 = lane & 15, l4 = lane >> 4;

  f32x4 acc[4][4];
#pragma unroll
  for (int i = 0; i < 4; ++i)
#pragma unroll
    for (int j = 0; j < 4; ++j) { f32x4 z = {0.f,0.f,0.f,0.f}; acc[i][j] = z; }

  const unsigned short* xmb = xm + (size_t)b * (64 * 32 * 34 * 8);

  auto stageX = [&](int c) {
    // 8kb*6r*34col = 1632 chunks of 16B; LDS byte = idx*16
#pragma unroll
    for (int r = 0; r < 4; ++r) {
      int idx = r * 512 + tid;
      if (idx < 1632) {
        int kb = idx / 204;
        int rem = idx - kb * 204;
        int rr = rem / 34;
        int col = rem - rr * 34;
        int hr = hg * 4 - 1 + rr;
        short8 v = {0,0,0,0,0,0,0,0};
        if (hr >= 0 && hr < 32) {
          size_t off = (((size_t)(c * 8 + kb) * 32 + hr) * 34 + col) * 8;
          v = *reinterpret_cast<const short8*>(xmb + off);
        }
        *reinterpret_cast<short8*>(xb + idx * 16) = v;
      }
    }
  };

  auto stageW = [&](int c, int t, int p) {
    int kb = wv;                    // one kb slice per wave
#pragma unroll
    for (int hh = 0; hh < 2; ++hh) {
      size_t gelem = ((((size_t)c * 9 + t) * 8 + kb) * 512 + cog * 128 + hh * 64 + lane) * 8;
      char* ldst = smem + 26112 + p * 16384 + (kb * 128 + hh * 64) * 16;
      gload_lds16(wpre + gelem, ldst);
    }
  };

  // prologue
  stageX(0);
  stageW(0, 0, 0);
  __syncthreads();

  for (int c = 0; c < 8; ++c) {
#pragma unroll
    for (int t = 0; t < 9; ++t) {
      int buf = (c + t) & 1;
      if (!(c == 7 && t == 8)) {              // prefetch next tap's W
        int cn = (t < 8) ? c : c + 1;
        int tn = (t < 8) ? t + 1 : 0;
        stageW(cn, tn, buf ^ 1);
      }
      int kh = t / 3, kw = t % 3;
      const char* wb = smem + 26112 + buf * 16384;

      short8 a[4];
#pragma unroll
      for (int mi = 0; mi < 4; ++mi) {
        int off = ((kp * 4 + l4) * 128 + wr * 64 + mi * 16 + l15) * 16;
        a[mi] = *reinterpret_cast<const short8*>(wb + off);
      }
#pragma unroll
      for (int nj = 0; nj < 4; ++nj) {
        int row4 = wc * 2 + (nj >> 1);
        int bo = (kp * 4 + l4) * 3264 + (row4 + kh) * 544 + ((nj & 1) * 16 + l15 + kw) * 16;
        short8 bfrag = *reinterpret_cast<const short8*>(xb + bo);
#pragma unroll
        for (int mi = 0; mi < 4; ++mi)
          acc[mi][nj] = __builtin_amdgcn_mfma_f32_16x16x32_bf16(a[mi], bfrag, acc[mi][nj], 0, 0, 0);
      }

      if (t == 8) {
        if (c < 7) {
          __syncthreads();          // everyone done reading xbuf
          stageX(c + 1);
          __syncthreads();          // xbuf + prefetched W ready
        }
      } else {
        __syncthreads();
      }
    }
  }

  // ---- K-split reduction (kp1 -> LDS -> kp0) ----
  __syncthreads();
#pragma unroll
  for (int p = 0; p < 2; ++p) {
    if (kp == 1 && wr == p) {
#pragma unroll
      for (int mi = 0; mi < 4; ++mi)
#pragma unroll
        for (int nj = 0; nj < 4; ++nj)
          *reinterpret_cast<f32x4*>(smem + wc * 16384 + (mi * 4 + nj) * 1024 + lane * 16) = acc[mi][nj];
    }
    __syncthreads();
    if (kp == 0 && wr == p) {
#pragma unroll
      for (int mi = 0; mi < 4; ++mi)
#pragma unroll
        for (int nj = 0; nj < 4; ++nj) {
          f32x4 v = *reinterpret_cast<const f32x4*>(smem + wc * 16384 + (mi * 4 + nj) * 1024 + lane * 16);
          acc[mi][nj] = acc[mi][nj] + v;
        }
    }
    __syncthreads();
  }

  // ---- epilogue: demod + bias, fp32 NCHW store ----
  if (kp == 0) {
    const float* rcpb = rcp + b * 512;
#pragma unroll
    for (int mi = 0; mi < 4; ++mi) {
      int ob = cog * 128 + wr * 64 + mi * 16 + l4 * 4;
      float rc[4], bi[4];
#pragma unroll
      for (int j = 0; j < 4; ++j) { rc[j] = rcpb[ob + j]; bi[j] = bias[ob + j]; }
#pragma unroll
      for (int nj = 0; nj < 4; ++nj) {
        int row4 = wc * 2 + (nj >> 1);
        int wcol = (nj & 1) * 16 + l15;
        int h = hg * 4 + row4;
#pragma unroll
        for (int j = 0; j < 4; ++j)
          out[(((size_t)b * 512 + ob + j) * 32 + h) * 32 + wcol] = acc[mi][nj][j] * rc[j] + bi[j];
      }
    }
  }
}

extern "C" void kernel_launch(void* const* d_in, const int* in_sizes, int n_in,
                              void* d_out, int out_size, void* d_ws, size_t ws_size,
                              hipStream_t stream) {
  const float* x    = (const float*)d_in[0];
  const float* ys   = (const float*)d_in[1];
  const float* w    = (const float*)d_in[2];
  const float* bias = (const float*)d_in[3];
  float* out = (float*)d_out;
  char* ws = (char*)d_ws;
  float* rcp = (float*)(ws + RCP_OFF);
  unsigned short* wpre = (unsigned short*)(ws + WPRE_OFF);
  unsigned short* xm   = (unsigned short*)(ws + XM_OFF);

  xs_kernel<<<512, 256, 0, stream>>>(w, ys, rcp);
  wpre_kernel<<<576, 256, 0, stream>>>(w, wpre);
  xm_kernel<<<512, 256, 0, stream>>>(x, ys, xm);
  conv_main<<<256, 512, 0, stream>>>(wpre, xm, rcp, bias, out);
}